// Round 17
// baseline (51.328 us; speedup 1.0000x reference)
//
#include <hip/hip_runtime.h>
#include <hip/hip_bf16.h>

// MLP_small_per_feature: per-feature MLP 1 -> 64 -> 64 -> 1, F=256, B=8192.
// v17 = v11 (best, 40.4us total) COLLAPSED TO ONE DISPATCH: the pack_params
// kernel (+inter-kernel gap, ~4-5us of every benchmarked call) is deleted;
// each wave gathers its o'-permuted w2/b2/w3 fragments DIRECTLY from the
// original fp32 tensors in the prologue:
//   - w2frag[t][ks] = bf16(w2[f][o'(t,l15)][ks*32+lg*8 .. +8])  (16 dwordx4,
//     L2-served: w2 totals 4MB; 64 waves/feature re-read 16KB from L2 ->
//     ~7TB/s aggregate, well under the 34TB/s L2 ceiling. v5's "fetch
//     explosion" was SPILLS (round-8 re-diagnosis), not this pattern.)
//   - b2c[t] = f32x4 at b2[f] + 32*(t>>1)+8*lg+4*(t&1)   (o' contiguous in r)
//   - w3f[ks] = bf16(w3[f][ks*32+lg*8 .. +8]); b3 splat into layer-3 C.
// Loop body/math byte-identical to v11 (absmax 0.03125).
//
// Plateau record (10 structures, rounds 1-16, all 40-43us): occupancy pushes
// x4, LDS-chain trims, layer1-as-MFMA, pipeline depth, persistence. Clean
// counters (v10): VALUBusy 44.6 + MfmaUtil 19.8 = ~64% combined port at
// ~2.3 waves/SIMD residency (machine-pinned). Spill canaries: SGPR<=48,
// WRITE~8MB.
//
// MFMA 16x16x32_bf16 layout (verified rounds 1-16):
//   A: row m = lane&15, k = (lane>>4)*8 + i
//   B: col n = lane&15, k = (lane>>4)*8 + i
//   C/D: col n = lane&15, row m = (lane>>4)*4 + r
//   o'(16t+m) = 32*(t>>1) + 8*(m>>2) + 4*(t&1) + (m&3)

namespace {

constexpr int kF = 256;
constexpr int kH = 64;
constexpr int kB = 8192;

constexpr int kFPB     = 4;               // features per block (one per wave)
constexpr int kRPB     = 128;             // rows per block
constexpr int kThreads = 256;             // 4 waves
constexpr int kFG      = kF / kFPB;       // 64 feature groups
constexpr int kRG      = kB / kRPB;       // 64 row groups
constexpr int kBlocks  = kFG * kRG;       // 4096
constexpr int kPasses  = kRPB / 16;       // 8
constexpr int kXP      = 10;              // xs pass-dim stride: conflict-free

using f32x2  = __attribute__((ext_vector_type(2))) float;
using f32x4  = __attribute__((ext_vector_type(4))) float;
using bf16x4 = __attribute__((ext_vector_type(4))) __bf16;
using bf16x8 = __attribute__((ext_vector_type(8))) __bf16;

__global__ __launch_bounds__(kThreads, 3)
void mlp_pf_v17(const float* __restrict__ x,
                const float* __restrict__ w1,
                const float* __restrict__ b1,
                const float* __restrict__ w2,
                const float* __restrict__ b2,
                const float* __restrict__ w3,
                const float* __restrict__ b3,
                float* __restrict__ out)
{
  __shared__ float xs[kFPB][16][kXP];     // 2.5 KB [feat][l15][pass]
  __shared__ float outb[kRPB][kFPB + 1];  // 2.56 KB (pad: conflict-free)

  const int tid  = (int)threadIdx.x;
  const int wid  = tid >> 6;
  const int lane = tid & 63;
  const int l15  = lane & 15;
  const int lg   = lane >> 4;

  const int fg = (int)blockIdx.x & (kFG - 1);  // consecutive blocks: same rows
  const int rg = (int)blockIdx.x >> 6;
  const int f  = fg * kFPB + wid;          // this wave's feature
  const int r0 = rg * kRPB;

  // ---- w2 fragments straight from fp32 w2, rows o'-permuted (issue first,
  // latency hides under staging + param loads; L2-served after first use) ----
  bf16x8 w2frag[4][2];
  {
    const float* w2f = w2 + (size_t)f * (kH * kH);
    const int o2base = 8 * (l15 >> 2) + (l15 & 3);   // o' minus the t terms
    #pragma unroll
    for (int t = 0; t < 4; ++t) {
      const int o2 = 32 * (t >> 1) + 4 * (t & 1) + o2base;
      #pragma unroll
      for (int ks = 0; ks < 2; ++ks) {
        const float* p = w2f + o2 * kH + ks * 32 + lg * 8;
        const f32x4 lo = *reinterpret_cast<const f32x4*>(p);
        const f32x4 hi = *reinterpret_cast<const f32x4*>(p + 4);
        w2frag[t][ks] = __builtin_shufflevector(
            __builtin_convertvector(lo, bf16x4),
            __builtin_convertvector(hi, bf16x4), 0, 1, 2, 3, 4, 5, 6, 7);
      }
    }
  }

  // ---- stage x tile (128 rows x 4 feats) -> pass-major LDS ----
  if (tid < kRPB) {
    const int rr = tid;
    const f32x4 v = *reinterpret_cast<const f32x4*>(
        x + (size_t)(r0 + rr) * kF + fg * kFPB);
    const int a = rr & 15, b = rr >> 4;
    xs[0][a][b] = v[0]; xs[1][a][b] = v[1];
    xs[2][a][b] = v[2]; xs[3][a][b] = v[3];
  }

  // ---- per-wave params, all direct from fp32 inputs ----
  f32x4 w1v[2][2], b1v[2][2];
  #pragma unroll
  for (int ks = 0; ks < 2; ++ks) {
    const float* pw = w1 + f * kH + ks * 32 + lg * 8;
    const float* pb = b1 + f * kH + ks * 32 + lg * 8;
    w1v[ks][0] = *reinterpret_cast<const f32x4*>(pw);
    w1v[ks][1] = *reinterpret_cast<const f32x4*>(pw + 4);
    b1v[ks][0] = *reinterpret_cast<const f32x4*>(pb);
    b1v[ks][1] = *reinterpret_cast<const f32x4*>(pb + 4);
  }
  // b2 C-operand: o'(t, lg*4 + r) = 32*(t>>1) + 8*lg + 4*(t&1) + r -> f32x4
  f32x4 b2c[4];
  #pragma unroll
  for (int t = 0; t < 4; ++t)
    b2c[t] = *reinterpret_cast<const f32x4*>(
        b2 + (size_t)f * kH + 32 * (t >> 1) + 8 * lg + 4 * (t & 1));
  // w3 A-fragments (bf16 on the fly)
  bf16x8 w3f[2];
  #pragma unroll
  for (int ks = 0; ks < 2; ++ks) {
    const float* p = w3 + (size_t)f * kH + ks * 32 + lg * 8;
    const f32x4 lo = *reinterpret_cast<const f32x4*>(p);
    const f32x4 hi = *reinterpret_cast<const f32x4*>(p + 4);
    w3f[ks] = __builtin_shufflevector(
        __builtin_convertvector(lo, bf16x4),
        __builtin_convertvector(hi, bf16x4), 0, 1, 2, 3, 4, 5, 6, 7);
  }
  const float b3v = b3[f];
  const f32x4 b3c = {b3v, b3v, b3v, b3v};

  __syncthreads();   // xs ready

  const f32x4 zero4 = {0.f, 0.f, 0.f, 0.f};
  float keep = 0.f;

  #pragma unroll
  for (int pp = 0; pp < kPasses / 2; ++pp) {
    // both passes' x values in one conflict-free ds_read_b64
    const f32x2 xp = *reinterpret_cast<const f32x2*>(&xs[wid][l15][2 * pp]);

    // ---- layer 1 for both passes (independent chains) ----
    bf16x8 h1A[2], h1B[2];
    #pragma unroll
    for (int ks = 0; ks < 2; ++ks) {
      f32x4 aA = w1v[ks][0] * xp[0] + b1v[ks][0];
      f32x4 bA = w1v[ks][1] * xp[0] + b1v[ks][1];
      f32x4 aB = w1v[ks][0] * xp[1] + b1v[ks][0];
      f32x4 bB = w1v[ks][1] * xp[1] + b1v[ks][1];
      aA = __builtin_elementwise_max(aA, zero4);
      bA = __builtin_elementwise_max(bA, zero4);
      aB = __builtin_elementwise_max(aB, zero4);
      bB = __builtin_elementwise_max(bB, zero4);
      h1A[ks] = __builtin_shufflevector(
          __builtin_convertvector(aA, bf16x4),
          __builtin_convertvector(bA, bf16x4), 0, 1, 2, 3, 4, 5, 6, 7);
      h1B[ks] = __builtin_shufflevector(
          __builtin_convertvector(aB, bf16x4),
          __builtin_convertvector(bB, bf16x4), 0, 1, 2, 3, 4, 5, 6, 7);
    }

    // ---- layer 2 (C = o'-permuted b2), A/B interleaved ----
    f32x4 accA[4], accB[4];
    #pragma unroll
    for (int t = 0; t < 4; ++t) {
      accA[t] = __builtin_amdgcn_mfma_f32_16x16x32_bf16(
          w2frag[t][0], h1A[0], b2c[t], 0, 0, 0);
      accB[t] = __builtin_amdgcn_mfma_f32_16x16x32_bf16(
          w2frag[t][0], h1B[0], b2c[t], 0, 0, 0);
      accA[t] = __builtin_amdgcn_mfma_f32_16x16x32_bf16(
          w2frag[t][1], h1A[1], accA[t], 0, 0, 0);
      accB[t] = __builtin_amdgcn_mfma_f32_16x16x32_bf16(
          w2frag[t][1], h1B[1], accB[t], 0, 0, 0);
    }

    // ---- relu + cvt: acc pairs form B-fragments of the layer-3 MFMA ----
    bf16x8 h2A0, h2A1, h2B0, h2B1;
    {
      const f32x4 rA0 = __builtin_elementwise_max(accA[0], zero4);
      const f32x4 rA1 = __builtin_elementwise_max(accA[1], zero4);
      const f32x4 rA2 = __builtin_elementwise_max(accA[2], zero4);
      const f32x4 rA3 = __builtin_elementwise_max(accA[3], zero4);
      const f32x4 rB0 = __builtin_elementwise_max(accB[0], zero4);
      const f32x4 rB1 = __builtin_elementwise_max(accB[1], zero4);
      const f32x4 rB2 = __builtin_elementwise_max(accB[2], zero4);
      const f32x4 rB3 = __builtin_elementwise_max(accB[3], zero4);
      h2A0 = __builtin_shufflevector(__builtin_convertvector(rA0, bf16x4),
                                     __builtin_convertvector(rA1, bf16x4),
                                     0, 1, 2, 3, 4, 5, 6, 7);
      h2A1 = __builtin_shufflevector(__builtin_convertvector(rA2, bf16x4),
                                     __builtin_convertvector(rA3, bf16x4),
                                     0, 1, 2, 3, 4, 5, 6, 7);
      h2B0 = __builtin_shufflevector(__builtin_convertvector(rB0, bf16x4),
                                     __builtin_convertvector(rB1, bf16x4),
                                     0, 1, 2, 3, 4, 5, 6, 7);
      h2B1 = __builtin_shufflevector(__builtin_convertvector(rB2, bf16x4),
                                     __builtin_convertvector(rB3, bf16x4),
                                     0, 1, 2, 3, 4, 5, 6, 7);
    }

    // ---- layer 3 via MFMA (C = b3 splat); D same across rows ----
    f32x4 dA = __builtin_amdgcn_mfma_f32_16x16x32_bf16(w3f[0], h2A0, b3c, 0, 0, 0);
    f32x4 dB = __builtin_amdgcn_mfma_f32_16x16x32_bf16(w3f[0], h2B0, b3c, 0, 0, 0);
    dA = __builtin_amdgcn_mfma_f32_16x16x32_bf16(w3f[1], h2A1, dA, 0, 0, 0);
    dB = __builtin_amdgcn_mfma_f32_16x16x32_bf16(w3f[1], h2B1, dB, 0, 0, 0);

    // ---- keep-trick: lane-group lg keeps pass quad*4+lg ----
    const int pA = 2 * pp, pB = 2 * pp + 1;
    keep = (lg == (pA & 3)) ? dA[0] : keep;
    keep = (lg == (pB & 3)) ? dB[0] : keep;
    if ((pB & 3) == 3) {
      outb[(pB >> 2) * 64 + lane][wid] = keep;   // b3 already folded in
    }
  }

  __syncthreads();

  // ---- output: one float4 (4 features) per row ----
  if (tid < kRPB) {
    const int rr = tid;
    const f32x4 v = {outb[rr][0], outb[rr][1], outb[rr][2], outb[rr][3]};
    *reinterpret_cast<f32x4*>(out + (size_t)(r0 + rr) * kF + fg * kFPB) = v;
  }
}

}  // namespace

extern "C" void kernel_launch(void* const* d_in, const int* in_sizes, int n_in,
                              void* d_out, int out_size, void* d_ws, size_t ws_size,
                              hipStream_t stream) {
  const float* x  = (const float*)d_in[0];
  const float* w1 = (const float*)d_in[1];
  const float* b1 = (const float*)d_in[2];
  const float* w2 = (const float*)d_in[3];
  const float* b2 = (const float*)d_in[4];
  const float* w3 = (const float*)d_in[5];
  const float* b3 = (const float*)d_in[6];
  float* out = (float*)d_out;

  hipLaunchKernelGGL(mlp_pf_v17, dim3(kBlocks), dim3(kThreads), 0, stream,
                     x, w1, b1, w2, b2, w3, b3, out);
}

// Round 18
// 39.958 us; speedup vs baseline: 1.2846x; 1.2846x over previous
//
#include <hip/hip_runtime.h>
#include <hip/hip_bf16.h>

// MLP_small_per_feature: per-feature MLP 1 -> 64 -> 64 -> 1, F=256, B=8192.
// v18 = v16's verified persistent-chunk structure at 4 blocks/CU.
// DECISIVE TEST: is the ~2.3 blocks/CU residency a churn artifact (short
// blocks, CP launch pipeline) or a hard cap? 1024 PERSISTENT blocks launch
// into an empty machine and live the whole kernel; resources allow 4/CU
// (VGPR ~84 <= 128, LDS 5.6KB x4). v16 (512 blocks, 2/CU) proved the
// persistent structure has no overhead penalty and 2.7x less total VALU
// work than v11 at the SAME 40us -- the bottleneck is dependency stalls at
// ~2 waves/SIMD, fixable only by residency.
//   bid = fg*16 + slab: XCD = bid%8 = slab%8 -> each XCD sees 2 x-slabs
//   (1 MB, L2-resident); w2p (2 MB) fits every L2.
// v17 lesson: packed w2p via prep kernel beats direct fp32 gather by 12us.
//
// MFMA 16x16x32_bf16 layout (verified rounds 1-17):
//   A: row m = lane&15, k = (lane>>4)*8 + i
//   B: col n = lane&15, k = (lane>>4)*8 + i
//   C/D: col n = lane&15, row m = (lane>>4)*4 + r
//   o'(16t+m) = 32*(t>>1) + 8*(m>>2) + 4*(t&1) + (m&3)
// Spill canaries: SGPR<=48, WRITE~8MB (v5/v6/v8 signatures).

namespace {

constexpr int kF = 256;
constexpr int kH = 64;
constexpr int kB = 8192;

constexpr int kFPB     = 4;               // features per block (one per wave)
constexpr int kRPC     = 128;             // rows per chunk
constexpr int kChunks  = 4;               // chunks per block
constexpr int kRPBlk   = kRPC * kChunks;  // 512 rows per block
constexpr int kThreads = 256;             // 4 waves
constexpr int kFG      = kF / kFPB;       // 64 feature groups
constexpr int kSlabs   = kB / kRPBlk;     // 16 row slabs
constexpr int kBlocks  = kFG * kSlabs;    // 1024 = 4 blocks/CU persistent
constexpr int kXP      = 12;              // pass-dim stride

using f32x4  = __attribute__((ext_vector_type(4))) float;
using bf16x4 = __attribute__((ext_vector_type(4))) __bf16;
using bf16x8 = __attribute__((ext_vector_type(8))) __bf16;

// ---- prep: pack w2 (o'-out-permuted, bf16, fragment-major), b2
// (o'-permuted, C-order), w3 (bf16). Verified v10-v16. ----
__global__ __launch_bounds__(256)
void pack_params(const float* __restrict__ w2, const float* __restrict__ b2,
                 const float* __restrict__ w3, __bf16* __restrict__ w2p,
                 float* __restrict__ b2p, __bf16* __restrict__ w3p)
{
  const int wid  = (int)threadIdx.x >> 6;
  const int lane = (int)threadIdx.x & 63;
  const int f    = (int)blockIdx.x * 4 + wid;
  const int l15  = lane & 15;
  const int lg   = lane >> 4;

  const float* w2f = w2 + (size_t)f * (kH * kH);
  #pragma unroll
  for (int t = 0; t < 4; ++t) {
    const int o2 = 32 * (t >> 1) + 8 * (l15 >> 2) + 4 * (t & 1) + (l15 & 3);
    #pragma unroll
    for (int ks = 0; ks < 2; ++ks) {
      const float* p = w2f + o2 * kH + ks * 32 + lg * 8;
      const f32x4 lo = *reinterpret_cast<const f32x4*>(p);
      const f32x4 hi = *reinterpret_cast<const f32x4*>(p + 4);
      const bf16x8 v = __builtin_shufflevector(
          __builtin_convertvector(lo, bf16x4),
          __builtin_convertvector(hi, bf16x4), 0, 1, 2, 3, 4, 5, 6, 7);
      *reinterpret_cast<bf16x8*>(
          w2p + (((size_t)f * 8 + t * 2 + ks) * 64 + lane) * 8) = v;
    }
  }

  {
    const int jt = lane >> 4, jlg = (lane >> 2) & 3, jr = lane & 3;
    const int o  = 32 * (jt >> 1) + 8 * jlg + 4 * (jt & 1) + jr;
    b2p[(size_t)f * kH + lane] = b2[(size_t)f * kH + o];
  }
  w3p[(size_t)f * kH + lane] = (__bf16)w3[(size_t)f * kH + lane];
}

__global__ __launch_bounds__(kThreads, 3)
void mlp_pf_v18(const float* __restrict__ x,
                const float* __restrict__ w1,
                const float* __restrict__ b1,
                const __bf16* __restrict__ w2p,
                const float* __restrict__ b2p,
                const __bf16* __restrict__ w3p,
                const float* __restrict__ b3,
                float* __restrict__ out)
{
  __shared__ float xs[kFPB][16][kXP];     // 3 KB [feat][l15][pass]
  __shared__ float outb[kRPC][kFPB + 1];  // 2.56 KB (pad: conflict-free)

  const int tid  = (int)threadIdx.x;
  const int wid  = tid >> 6;
  const int lane = tid & 63;
  const int l15  = lane & 15;
  const int lg   = lane >> 4;

  const int fg   = (int)blockIdx.x >> 4;       // 0..63
  const int slab = (int)blockIdx.x & 15;       // 0..15; XCD = slab%8
  const int f    = fg * kFPB + wid;            // this wave's feature
  const int rs0  = slab * kRPBlk;              // slab row base

  // ================= PROLOGUE (paid once per 512 rows) =================
  bf16x8 w2frag[4][2];
  {
    const __bf16* base = w2p + ((size_t)f * 8 * 64 + lane) * 8;
    #pragma unroll
    for (int t = 0; t < 4; ++t)
      #pragma unroll
      for (int ks = 0; ks < 2; ++ks)
        w2frag[t][ks] = *reinterpret_cast<const bf16x8*>(
            base + (size_t)(t * 2 + ks) * 64 * 8);
  }

  f32x4 w1v[2][2], b1v[2][2];
  #pragma unroll
  for (int ks = 0; ks < 2; ++ks) {
    const float* pw = w1 + f * kH + ks * 32 + lg * 8;
    const float* pb = b1 + f * kH + ks * 32 + lg * 8;
    w1v[ks][0] = *reinterpret_cast<const f32x4*>(pw);
    w1v[ks][1] = *reinterpret_cast<const f32x4*>(pw + 4);
    b1v[ks][0] = *reinterpret_cast<const f32x4*>(pb);
    b1v[ks][1] = *reinterpret_cast<const f32x4*>(pb + 4);
  }
  f32x4 b2c[4];
  #pragma unroll
  for (int t = 0; t < 4; ++t)
    b2c[t] = *reinterpret_cast<const f32x4*>(b2p + f * kH + t * 16 + lg * 4);
  bf16x8 w3f[2];
  #pragma unroll
  for (int ks = 0; ks < 2; ++ks)
    w3f[ks] = *reinterpret_cast<const bf16x8*>(w3p + f * kH + ks * 32 + lg * 8);
  const float b3v = b3[f];
  const f32x4 b3c = {b3v, b3v, b3v, b3v};

  const f32x4 zero4 = {0.f, 0.f, 0.f, 0.f};
  float keep = 0.f;

  struct PairH1 { bf16x8 a0, a1, b0, b1; };

  auto mk = [&](float xa, float xb) -> PairH1 {
    PairH1 r;
    #pragma unroll
    for (int ks = 0; ks < 2; ++ks) {
      f32x4 aA = w1v[ks][0] * xa + b1v[ks][0];
      f32x4 bA = w1v[ks][1] * xa + b1v[ks][1];
      f32x4 aB = w1v[ks][0] * xb + b1v[ks][0];
      f32x4 bB = w1v[ks][1] * xb + b1v[ks][1];
      aA = __builtin_elementwise_max(aA, zero4);
      bA = __builtin_elementwise_max(bA, zero4);
      aB = __builtin_elementwise_max(aB, zero4);
      bB = __builtin_elementwise_max(bB, zero4);
      const bf16x8 hA = __builtin_shufflevector(
          __builtin_convertvector(aA, bf16x4),
          __builtin_convertvector(bA, bf16x4), 0, 1, 2, 3, 4, 5, 6, 7);
      const bf16x8 hB = __builtin_shufflevector(
          __builtin_convertvector(aB, bf16x4),
          __builtin_convertvector(bB, bf16x4), 0, 1, 2, 3, 4, 5, 6, 7);
      if (ks == 0) { r.a0 = hA; r.b0 = hB; } else { r.a1 = hA; r.b1 = hB; }
    }
    return r;
  };

  auto pack2 = [&](const f32x4& a, const f32x4& b) -> bf16x8 {
    return __builtin_shufflevector(
        __builtin_convertvector(__builtin_elementwise_max(a, zero4), bf16x4),
        __builtin_convertvector(__builtin_elementwise_max(b, zero4), bf16x4),
        0, 1, 2, 3, 4, 5, 6, 7);
  };

  auto fin = [&](const PairH1& h, int PI) {
    f32x4 accA[4], accB[4];
    #pragma unroll
    for (int t = 0; t < 4; ++t) {
      accA[t] = __builtin_amdgcn_mfma_f32_16x16x32_bf16(
          w2frag[t][0], h.a0, b2c[t], 0, 0, 0);
      accB[t] = __builtin_amdgcn_mfma_f32_16x16x32_bf16(
          w2frag[t][0], h.b0, b2c[t], 0, 0, 0);
      accA[t] = __builtin_amdgcn_mfma_f32_16x16x32_bf16(
          w2frag[t][1], h.a1, accA[t], 0, 0, 0);
      accB[t] = __builtin_amdgcn_mfma_f32_16x16x32_bf16(
          w2frag[t][1], h.b1, accB[t], 0, 0, 0);
    }
    const bf16x8 h2A0 = pack2(accA[0], accA[1]);
    const bf16x8 h2A1 = pack2(accA[2], accA[3]);
    const bf16x8 h2B0 = pack2(accB[0], accB[1]);
    const bf16x8 h2B1 = pack2(accB[2], accB[3]);

    f32x4 dA = __builtin_amdgcn_mfma_f32_16x16x32_bf16(w3f[0], h2A0, b3c, 0, 0, 0);
    f32x4 dB = __builtin_amdgcn_mfma_f32_16x16x32_bf16(w3f[0], h2B0, b3c, 0, 0, 0);
    dA = __builtin_amdgcn_mfma_f32_16x16x32_bf16(w3f[1], h2A1, dA, 0, 0, 0);
    dB = __builtin_amdgcn_mfma_f32_16x16x32_bf16(w3f[1], h2B1, dB, 0, 0, 0);

    const int pA = 2 * PI, pB = 2 * PI + 1;
    keep = (lg == (pA & 3)) ? dA[0] : keep;
    keep = (lg == (pB & 3)) ? dB[0] : keep;
    if ((pB & 3) == 3) {
      outb[(pB >> 2) * 64 + lane][wid] = keep;   // b3 folded in
    }
  };

  // ================= 4 chunks of the verified body =================
  #pragma unroll 1
  for (int ck = 0; ck < kChunks; ++ck) {
    const int r0 = rs0 + ck * kRPC;

    if (tid < kRPC) {
      const int rr = tid;
      const f32x4 v = *reinterpret_cast<const f32x4*>(
          x + (size_t)(r0 + rr) * kF + fg * kFPB);
      const int a = rr & 15, b = rr >> 4;
      xs[0][a][b] = v[0]; xs[1][a][b] = v[1];
      xs[2][a][b] = v[2]; xs[3][a][b] = v[3];
    }
    __syncthreads();   // xs ready

    const f32x4 xq0 = *reinterpret_cast<const f32x4*>(&xs[wid][l15][0]);
    const f32x4 xq1 = *reinterpret_cast<const f32x4*>(&xs[wid][l15][4]);

    PairH1 c  = mk(xq0[0], xq0[1]);
    PairH1 n1 = mk(xq0[2], xq0[3]);
    fin(c, 0);
    PairH1 n2 = mk(xq1[0], xq1[1]);
    fin(n1, 1);
    PairH1 n3 = mk(xq1[2], xq1[3]);
    fin(n2, 2);
    fin(n3, 3);

    __syncthreads();   // outb ready

    if (tid < kRPC) {
      const int rr = tid;
      const f32x4 v = {outb[rr][0], outb[rr][1], outb[rr][2], outb[rr][3]};
      *reinterpret_cast<f32x4*>(out + (size_t)(r0 + rr) * kF + fg * kFPB) = v;
    }
    __syncthreads();   // protect xs/outb for next chunk
  }
}

}  // namespace

extern "C" void kernel_launch(void* const* d_in, const int* in_sizes, int n_in,
                              void* d_out, int out_size, void* d_ws, size_t ws_size,
                              hipStream_t stream) {
  const float* x  = (const float*)d_in[0];
  const float* w1 = (const float*)d_in[1];
  const float* b1 = (const float*)d_in[2];
  const float* w2 = (const float*)d_in[3];
  const float* b2 = (const float*)d_in[4];
  const float* w3 = (const float*)d_in[5];
  const float* b3 = (const float*)d_in[6];
  float* out = (float*)d_out;

  __bf16* w2p = (__bf16*)d_ws;                           // 2 MB
  float*  b2p = (float*)((char*)d_ws + (2u << 20));      // 64 KB
  __bf16* w3p = (__bf16*)((char*)d_ws + (2u << 20) + (64u << 10));  // 32 KB

  hipLaunchKernelGGL(pack_params, dim3(kF / 4), dim3(256), 0, stream,
                     w2, b2, w3, w2p, b2p, w3p);
  hipLaunchKernelGGL(mlp_pf_v18, dim3(kBlocks), dim3(kThreads), 0, stream,
                     x, w1, b1, w2p, b2p, w3p, b3, out);
}

// Round 20
// 39.683 us; speedup vs baseline: 1.2934x; 1.0069x over previous
//
#include <hip/hip_runtime.h>
#include <hip/hip_bf16.h>

// MLP_small_per_feature: per-feature MLP 1 -> 64 -> 64 -> 1, F=256, B=8192.
// v20 = v18 byte-for-byte (best verified: 39.96us, absmax 0.03125).
// v19's cooperative-launch fusion failed in this harness (graph-capture:
// kernel never executed, output stayed poisoned) -- reverted per plan.
//
// Final structure: pack_params dispatch (w2 -> bf16 o'-permuted fragment-
// major w2p in d_ws; b2 -> o'-permuted C-order; w3 -> bf16) + persistent
// main kernel (1024 blocks = 4/CU, 4 chunks x 128 rows, 4 waves/block,
// one feature per wave, 2-pass-pair ILP pipeline, layer-2 and layer-3 on
// MFMA with b2/b3 folded into C operands, keep-trick store + outb exchange).
//
// Plateau record (rounds 1-18, 11 structures, all 40-43us): occupancy x5,
// LDS-chain trims, layer1-as-MFMA, pipeline depth, fixed-cost amortization,
// single-dispatch fp32 gather, cooperative fusion. Counters at plateau:
// VALUBusy ~40-45 + MfmaUtil ~15-20 (~64% combined), HBM <17%, no spills,
// no bank conflicts, residency machine-pinned ~2.3 waves/SIMD.
//
// MFMA 16x16x32_bf16 layout (verified rounds 1-18):
//   A: row m = lane&15, k = (lane>>4)*8 + i
//   B: col n = lane&15, k = (lane>>4)*8 + i
//   C/D: col n = lane&15, row m = (lane>>4)*4 + r
//   o'(16t+m) = 32*(t>>1) + 8*(m>>2) + 4*(t&1) + (m&3)

namespace {

constexpr int kF = 256;
constexpr int kH = 64;
constexpr int kB = 8192;

constexpr int kFPB     = 4;               // features per block (one per wave)
constexpr int kRPC     = 128;             // rows per chunk
constexpr int kChunks  = 4;               // chunks per block
constexpr int kRPBlk   = kRPC * kChunks;  // 512 rows per block
constexpr int kThreads = 256;             // 4 waves
constexpr int kFG      = kF / kFPB;       // 64 feature groups
constexpr int kSlabs   = kB / kRPBlk;     // 16 row slabs
constexpr int kBlocks  = kFG * kSlabs;    // 1024 = 4 blocks/CU persistent
constexpr int kXP      = 12;              // pass-dim stride

using f32x4  = __attribute__((ext_vector_type(4))) float;
using bf16x4 = __attribute__((ext_vector_type(4))) __bf16;
using bf16x8 = __attribute__((ext_vector_type(8))) __bf16;

// ---- prep: pack w2 (o'-out-permuted, bf16, fragment-major), b2
// (o'-permuted, C-order), w3 (bf16). Verified v10-v18. ----
__global__ __launch_bounds__(256)
void pack_params(const float* __restrict__ w2, const float* __restrict__ b2,
                 const float* __restrict__ w3, __bf16* __restrict__ w2p,
                 float* __restrict__ b2p, __bf16* __restrict__ w3p)
{
  const int wid  = (int)threadIdx.x >> 6;
  const int lane = (int)threadIdx.x & 63;
  const int f    = (int)blockIdx.x * 4 + wid;
  const int l15  = lane & 15;
  const int lg   = lane >> 4;

  const float* w2f = w2 + (size_t)f * (kH * kH);
  #pragma unroll
  for (int t = 0; t < 4; ++t) {
    const int o2 = 32 * (t >> 1) + 8 * (l15 >> 2) + 4 * (t & 1) + (l15 & 3);
    #pragma unroll
    for (int ks = 0; ks < 2; ++ks) {
      const float* p = w2f + o2 * kH + ks * 32 + lg * 8;
      const f32x4 lo = *reinterpret_cast<const f32x4*>(p);
      const f32x4 hi = *reinterpret_cast<const f32x4*>(p + 4);
      const bf16x8 v = __builtin_shufflevector(
          __builtin_convertvector(lo, bf16x4),
          __builtin_convertvector(hi, bf16x4), 0, 1, 2, 3, 4, 5, 6, 7);
      *reinterpret_cast<bf16x8*>(
          w2p + (((size_t)f * 8 + t * 2 + ks) * 64 + lane) * 8) = v;
    }
  }

  {
    const int jt = lane >> 4, jlg = (lane >> 2) & 3, jr = lane & 3;
    const int o  = 32 * (jt >> 1) + 8 * jlg + 4 * (jt & 1) + jr;
    b2p[(size_t)f * kH + lane] = b2[(size_t)f * kH + o];
  }
  w3p[(size_t)f * kH + lane] = (__bf16)w3[(size_t)f * kH + lane];
}

__global__ __launch_bounds__(kThreads, 3)
void mlp_pf_v20(const float* __restrict__ x,
                const float* __restrict__ w1,
                const float* __restrict__ b1,
                const __bf16* __restrict__ w2p,
                const float* __restrict__ b2p,
                const __bf16* __restrict__ w3p,
                const float* __restrict__ b3,
                float* __restrict__ out)
{
  __shared__ float xs[kFPB][16][kXP];     // 3 KB [feat][l15][pass]
  __shared__ float outb[kRPC][kFPB + 1];  // 2.56 KB (pad: conflict-free)

  const int tid  = (int)threadIdx.x;
  const int wid  = tid >> 6;
  const int lane = tid & 63;
  const int l15  = lane & 15;
  const int lg   = lane >> 4;

  const int fg   = (int)blockIdx.x >> 4;       // 0..63
  const int slab = (int)blockIdx.x & 15;       // 0..15; XCD = slab%8
  const int f    = fg * kFPB + wid;            // this wave's feature
  const int rs0  = slab * kRPBlk;              // slab row base

  // ================= PROLOGUE (paid once per 512 rows) =================
  bf16x8 w2frag[4][2];
  {
    const __bf16* base = w2p + ((size_t)f * 8 * 64 + lane) * 8;
    #pragma unroll
    for (int t = 0; t < 4; ++t)
      #pragma unroll
      for (int ks = 0; ks < 2; ++ks)
        w2frag[t][ks] = *reinterpret_cast<const bf16x8*>(
            base + (size_t)(t * 2 + ks) * 64 * 8);
  }

  f32x4 w1v[2][2], b1v[2][2];
  #pragma unroll
  for (int ks = 0; ks < 2; ++ks) {
    const float* pw = w1 + f * kH + ks * 32 + lg * 8;
    const float* pb = b1 + f * kH + ks * 32 + lg * 8;
    w1v[ks][0] = *reinterpret_cast<const f32x4*>(pw);
    w1v[ks][1] = *reinterpret_cast<const f32x4*>(pw + 4);
    b1v[ks][0] = *reinterpret_cast<const f32x4*>(pb);
    b1v[ks][1] = *reinterpret_cast<const f32x4*>(pb + 4);
  }
  f32x4 b2c[4];
  #pragma unroll
  for (int t = 0; t < 4; ++t)
    b2c[t] = *reinterpret_cast<const f32x4*>(b2p + f * kH + t * 16 + lg * 4);
  bf16x8 w3f[2];
  #pragma unroll
  for (int ks = 0; ks < 2; ++ks)
    w3f[ks] = *reinterpret_cast<const bf16x8*>(w3p + f * kH + ks * 32 + lg * 8);
  const float b3v = b3[f];
  const f32x4 b3c = {b3v, b3v, b3v, b3v};

  const f32x4 zero4 = {0.f, 0.f, 0.f, 0.f};
  float keep = 0.f;

  struct PairH1 { bf16x8 a0, a1, b0, b1; };

  auto mk = [&](float xa, float xb) -> PairH1 {
    PairH1 r;
    #pragma unroll
    for (int ks = 0; ks < 2; ++ks) {
      f32x4 aA = w1v[ks][0] * xa + b1v[ks][0];
      f32x4 bA = w1v[ks][1] * xa + b1v[ks][1];
      f32x4 aB = w1v[ks][0] * xb + b1v[ks][0];
      f32x4 bB = w1v[ks][1] * xb + b1v[ks][1];
      aA = __builtin_elementwise_max(aA, zero4);
      bA = __builtin_elementwise_max(bA, zero4);
      aB = __builtin_elementwise_max(aB, zero4);
      bB = __builtin_elementwise_max(bB, zero4);
      const bf16x8 hA = __builtin_shufflevector(
          __builtin_convertvector(aA, bf16x4),
          __builtin_convertvector(bA, bf16x4), 0, 1, 2, 3, 4, 5, 6, 7);
      const bf16x8 hB = __builtin_shufflevector(
          __builtin_convertvector(aB, bf16x4),
          __builtin_convertvector(bB, bf16x4), 0, 1, 2, 3, 4, 5, 6, 7);
      if (ks == 0) { r.a0 = hA; r.b0 = hB; } else { r.a1 = hA; r.b1 = hB; }
    }
    return r;
  };

  auto pack2 = [&](const f32x4& a, const f32x4& b) -> bf16x8 {
    return __builtin_shufflevector(
        __builtin_convertvector(__builtin_elementwise_max(a, zero4), bf16x4),
        __builtin_convertvector(__builtin_elementwise_max(b, zero4), bf16x4),
        0, 1, 2, 3, 4, 5, 6, 7);
  };

  auto fin = [&](const PairH1& h, int PI) {
    f32x4 accA[4], accB[4];
    #pragma unroll
    for (int t = 0; t < 4; ++t) {
      accA[t] = __builtin_amdgcn_mfma_f32_16x16x32_bf16(
          w2frag[t][0], h.a0, b2c[t], 0, 0, 0);
      accB[t] = __builtin_amdgcn_mfma_f32_16x16x32_bf16(
          w2frag[t][0], h.b0, b2c[t], 0, 0, 0);
      accA[t] = __builtin_amdgcn_mfma_f32_16x16x32_bf16(
          w2frag[t][1], h.a1, accA[t], 0, 0, 0);
      accB[t] = __builtin_amdgcn_mfma_f32_16x16x32_bf16(
          w2frag[t][1], h.b1, accB[t], 0, 0, 0);
    }
    const bf16x8 h2A0 = pack2(accA[0], accA[1]);
    const bf16x8 h2A1 = pack2(accA[2], accA[3]);
    const bf16x8 h2B0 = pack2(accB[0], accB[1]);
    const bf16x8 h2B1 = pack2(accB[2], accB[3]);

    f32x4 dA = __builtin_amdgcn_mfma_f32_16x16x32_bf16(w3f[0], h2A0, b3c, 0, 0, 0);
    f32x4 dB = __builtin_amdgcn_mfma_f32_16x16x32_bf16(w3f[0], h2B0, b3c, 0, 0, 0);
    dA = __builtin_amdgcn_mfma_f32_16x16x32_bf16(w3f[1], h2A1, dA, 0, 0, 0);
    dB = __builtin_amdgcn_mfma_f32_16x16x32_bf16(w3f[1], h2B1, dB, 0, 0, 0);

    const int pA = 2 * PI, pB = 2 * PI + 1;
    keep = (lg == (pA & 3)) ? dA[0] : keep;
    keep = (lg == (pB & 3)) ? dB[0] : keep;
    if ((pB & 3) == 3) {
      outb[(pB >> 2) * 64 + lane][wid] = keep;   // b3 folded in
    }
  };

  // ================= 4 chunks of the verified body =================
  #pragma unroll 1
  for (int ck = 0; ck < kChunks; ++ck) {
    const int r0 = rs0 + ck * kRPC;

    if (tid < kRPC) {
      const int rr = tid;
      const f32x4 v = *reinterpret_cast<const f32x4*>(
          x + (size_t)(r0 + rr) * kF + fg * kFPB);
      const int a = rr & 15, b = rr >> 4;
      xs[0][a][b] = v[0]; xs[1][a][b] = v[1];
      xs[2][a][b] = v[2]; xs[3][a][b] = v[3];
    }
    __syncthreads();   // xs ready

    const f32x4 xq0 = *reinterpret_cast<const f32x4*>(&xs[wid][l15][0]);
    const f32x4 xq1 = *reinterpret_cast<const f32x4*>(&xs[wid][l15][4]);

    PairH1 c  = mk(xq0[0], xq0[1]);
    PairH1 n1 = mk(xq0[2], xq0[3]);
    fin(c, 0);
    PairH1 n2 = mk(xq1[0], xq1[1]);
    fin(n1, 1);
    PairH1 n3 = mk(xq1[2], xq1[3]);
    fin(n2, 2);
    fin(n3, 3);

    __syncthreads();   // outb ready

    if (tid < kRPC) {
      const int rr = tid;
      const f32x4 v = {outb[rr][0], outb[rr][1], outb[rr][2], outb[rr][3]};
      *reinterpret_cast<f32x4*>(out + (size_t)(r0 + rr) * kF + fg * kFPB) = v;
    }
    __syncthreads();   // protect xs/outb for next chunk
  }
}

}  // namespace

extern "C" void kernel_launch(void* const* d_in, const int* in_sizes, int n_in,
                              void* d_out, int out_size, void* d_ws, size_t ws_size,
                              hipStream_t stream) {
  const float* x  = (const float*)d_in[0];
  const float* w1 = (const float*)d_in[1];
  const float* b1 = (const float*)d_in[2];
  const float* w2 = (const float*)d_in[3];
  const float* b2 = (const float*)d_in[4];
  const float* w3 = (const float*)d_in[5];
  const float* b3 = (const float*)d_in[6];
  float* out = (float*)d_out;

  __bf16* w2p = (__bf16*)d_ws;                           // 2 MB
  float*  b2p = (float*)((char*)d_ws + (2u << 20));      // 64 KB
  __bf16* w3p = (__bf16*)((char*)d_ws + (2u << 20) + (64u << 10));  // 32 KB

  hipLaunchKernelGGL(pack_params, dim3(kF / 4), dim3(256), 0, stream,
                     w2, b2, w3, w2p, b2p, w3p);
  hipLaunchKernelGGL(mlp_pf_v20, dim3(kBlocks), dim3(kThreads), 0, stream,
                     x, w1, b1, w2p, b2p, w3p, b3, out);
}